// Round 9
// baseline (182.111 us; speedup 1.0000x reference)
//
#include <hip/hip_runtime.h>
#include <hip/hip_bf16.h>

// Problem dims (fixed by reference)
#define B_ROWS   8192
#define K_DIM    2048
#define OUT_COLS 4096
#define EPS      1e-5f

// Occupancy-first structure: 128x256 tile, BK=32, 8 waves (2M x 4N, 64x64 each),
// acc=64 VGPR -> 2 blocks/CU (4 waves/SIMD), triple-buffered LDS (76 KB),
// counted vmcnt(3), one barrier per K-tile. TLP hides staging/read latency.
#define BM 128
#define BN 256
#define BK 32
#define NKT (K_DIM / BK)   // 64 K-tiles

using f32x4  = __attribute__((ext_vector_type(4))) float;
using bf16x8 = __attribute__((ext_vector_type(8))) short;   // 8 bf16 = 4 VGPRs

__device__ __forceinline__ unsigned short f2bf_rn(float f) {
    unsigned u = __builtin_bit_cast(unsigned, f);
    u += 0x7FFFu + ((u >> 16) & 1u);   // RNE (inputs finite)
    return (unsigned short)(u >> 16);
}

__global__ void cvt_all(const float* __restrict__ x, const float* __restrict__ w,
                        unsigned short* __restrict__ xb, unsigned short* __restrict__ wb) {
    const int n4x = (B_ROWS * K_DIM) / 4;
    const int n4w = (OUT_COLS * K_DIM) / 4;
    int stride = gridDim.x * blockDim.x;
    for (int i = blockIdx.x * blockDim.x + threadIdx.x; i < n4x + n4w; i += stride) {
        const float4* src; ushort4* dst; int j;
        if (i < n4x) { src = (const float4*)x; dst = (ushort4*)xb; j = i; }
        else         { src = (const float4*)w; dst = (ushort4*)wb; j = i - n4x; }
        float4 v = src[j];
        ushort4 r;
        r.x = f2bf_rn(v.x); r.y = f2bf_rn(v.y); r.z = f2bf_rn(v.z); r.w = f2bf_rn(v.w);
        dst[j] = r;
    }
}

__device__ __forceinline__ void gload16(const unsigned short* src, unsigned short* lds) {
    __builtin_amdgcn_global_load_lds((const __attribute__((address_space(1))) void*)src,
                                     (__attribute__((address_space(3))) void*)lds,
                                     16, 0, 0);
}

// 16-lane row sum via DPP row_ror (pure VALU): all 16 lanes get the total
__device__ __forceinline__ float rowsum16(float v) {
    int x;
    x = __builtin_amdgcn_update_dpp(0, __builtin_bit_cast(int, v), 0x121, 0xF, 0xF, true);
    v += __builtin_bit_cast(float, x);
    x = __builtin_amdgcn_update_dpp(0, __builtin_bit_cast(int, v), 0x122, 0xF, 0xF, true);
    v += __builtin_bit_cast(float, x);
    x = __builtin_amdgcn_update_dpp(0, __builtin_bit_cast(int, v), 0x124, 0xF, 0xF, true);
    v += __builtin_bit_cast(float, x);
    x = __builtin_amdgcn_update_dpp(0, __builtin_bit_cast(int, v), 0x128, 0xF, 0xF, true);
    v += __builtin_bit_cast(float, x);
    return v;
}

#define VW3   asm volatile("s_waitcnt vmcnt(3)" ::: "memory")
#define VWALL asm volatile("s_waitcnt vmcnt(0)" ::: "memory")
#define BAR   __builtin_amdgcn_s_barrier()

// stage one full K-tile (A: 128x32 = 1 load/thread, B: 256x32 = 2 loads/thread);
// linear LDS dest, source chunk pre-permuted by c ^= (row>>1)&3 within each 64B row
#define STAGE(AOFF, BOFF, KT) do {                                                  \
    gload16(Ag + (KT)*32 + goffA,  &As[(AOFF) + ldsA]);                             \
    gload16(Bg + (KT)*32 + goffB0, &Bs[(BOFF) + ldsB0]);                            \
    gload16(Bg + (KT)*32 + goffB1, &Bs[(BOFF) + ldsB1]);                            \
  } while (0)

// one K-tile: stage (kt+2) -> read 4 A-frags + 4 B-frags -> 16 MFMA -> vmcnt(3) -> barrier
#define KTILE(AOFF, BOFF, SAOFF, SBOFF, KT2) do {                                   \
    bf16x8 af[4], bb[4];                                                            \
    STAGE(SAOFF, SBOFF, KT2);                                                       \
    _Pragma("unroll") for (int m = 0; m < 4; ++m)                                   \
        af[m] = *(const bf16x8*)&As[(AOFF) + arow + m*512 + csw];                   \
    _Pragma("unroll") for (int n = 0; n < 4; ++n)                                   \
        bb[n] = *(const bf16x8*)&Bs[(BOFF) + brw + n*512 + csw];                    \
    __builtin_amdgcn_s_setprio(1);                                                  \
    _Pragma("unroll") for (int m = 0; m < 4; ++m)                                   \
      _Pragma("unroll") for (int n = 0; n < 4; ++n)                                 \
        acc[m][n] = __builtin_amdgcn_mfma_f32_16x16x32_bf16(                        \
            af[m], bb[n], acc[m][n], 0, 0, 0);                                      \
    __builtin_amdgcn_s_setprio(0);                                                  \
    VW3;                                                                            \
    BAR;                                                                            \
  } while (0)

__global__ __launch_bounds__(512, 4) void gemm_gn(const unsigned short* __restrict__ A,
                                                  const unsigned short* __restrict__ Bw,
                                                  const float* __restrict__ bias,
                                                  float* __restrict__ out) {
    __shared__ __align__(16) unsigned short As[3 * 4096];   // 3 x 8 KB  (128x32)
    __shared__ __align__(16) unsigned short Bs[3 * 8192];   // 3 x 16 KB (256x32)
    __shared__ __align__(16) float redbuf[128 * 8];         // 4 KB GN scratch

    const int tid  = threadIdx.x;
    const int lane = tid & 63;
    const int wave = tid >> 6;        // 0..7
    const int wr   = wave >> 2;       // 0..1 (M)
    const int wcn  = wave & 3;        // 0..3 (N)
    const int l16  = lane & 15;
    const int lhi  = lane >> 4;

    // T1: XCD-aware bijective swizzle (grid 1024, 1024 % 8 == 0);
    // 16 consecutive swz per XCD share brow -> A-panel L2 locality
    const int bid  = blockIdx.x;
    const int swz  = (bid & 7) * (gridDim.x >> 3) + (bid >> 3);
    const int brow = swz >> 4;        // 0..63
    const int bcol = swz & 15;        // 0..15

    // staging offsets: slot s -> row s>>2, chunk (s&3)^((row>>1)&3)  (16B chunks)
    int goffA, ldsA, goffB0, goffB1, ldsB0, ldsB1;
    {
        int sA = tid;              int rA = sA >> 2;
        goffA  = rA * K_DIM + (((sA & 3) ^ ((rA >> 1) & 3)) * 8);
        ldsA   = sA * 8;
        int s0 = tid;              int r0 = s0 >> 2;
        int s1 = tid + 512;        int r1 = s1 >> 2;
        goffB0 = r0 * K_DIM + (((s0 & 3) ^ ((r0 >> 1) & 3)) * 8);
        goffB1 = r1 * K_DIM + (((s1 & 3) ^ ((r1 >> 1) & 3)) * 8);
        ldsB0  = s0 * 8;
        ldsB1  = s1 * 8;
    }
    const unsigned short* Ag = A  + (size_t)brow * BM * K_DIM;
    const unsigned short* Bg = Bw + (size_t)bcol * BN * K_DIM;

    // fragment-read offsets: row r, logical chunk lhi -> physical chunk lhi^((r>>1)&3);
    // (r>>1)&3 == (l16>>1)&3 for all frags (m/n/wave offsets are multiples of 16 rows)
    const int csw  = (lhi ^ ((l16 >> 1) & 3)) * 8;
    const int arow = (wr * 64 + l16) * 32;
    const int brw  = (wcn * 64 + l16) * 32;

    // bias folded into accumulator init (all 4 C-regs of acc[m][n] share one column)
    f32x4 acc[4][4];
    {
        float bv[4];
        #pragma unroll
        for (int n = 0; n < 4; ++n)
            bv[n] = bias[bcol * BN + wcn * 64 + n * 16 + l16];
        #pragma unroll
        for (int m = 0; m < 4; ++m)
            #pragma unroll
            for (int n = 0; n < 4; ++n)
                #pragma unroll
                for (int j = 0; j < 4; ++j)
                    acc[m][n][j] = bv[n];
    }

    // ---- prologue: buf0 <- kt0, buf1 <- kt1; drain to 3 => kt0 landed
    STAGE(0, 0, 0);
    STAGE(4096, 8192, 1);
    VW3;
    BAR;

    // ---- main loop: 63 K-tiles in 21 statically-indexed triples ----
    // iter t: read buf[t%3], stage kt=t+2 into buf[(t+2)%3]; vmcnt(3) leaves the
    // newest K-tile's 3 loads in flight, drains the previous one (landed+barrier'd
    // before its consumer iteration). t=62 stages a wrapped dummy (kt 0 -> buf1).
    #pragma unroll 1
    for (int it = 0; it < 21; ++it) {
        const int kt = it * 3;
        KTILE(0,    0,     8192, 16384, kt + 2);
        KTILE(4096, 8192,  0,    0,     kt + 3);
        KTILE(8192, 16384, 4096, 8192,  (kt + 4) & 63);
    }
    // ---- peeled final K-tile (kt=63 in buf0), no stage, no barrier needed
    {
        bf16x8 af[4], bb[4];
        #pragma unroll
        for (int m = 0; m < 4; ++m)
            af[m] = *(const bf16x8*)&As[arow + m*512 + csw];
        #pragma unroll
        for (int n = 0; n < 4; ++n)
            bb[n] = *(const bf16x8*)&Bs[brw + n*512 + csw];
        #pragma unroll
        for (int m = 0; m < 4; ++m)
            #pragma unroll
            for (int n = 0; n < 4; ++n)
                acc[m][n] = __builtin_amdgcn_mfma_f32_16x16x32_bf16(
                    af[m], bb[n], acc[m][n], 0, 0, 0);
    }

    // ---- epilogue: GroupNorm over 128-col groups (block-local), clip, store ----
    // pass 1: per-row (s, s2) over this wave's 64 cols; DPP reduce into redbuf.
    // C/D layout (16x16): col = lane&15, row = (lane>>4)*4 + j
    #pragma unroll
    for (int m = 0; m < 4; ++m) {
        #pragma unroll
        for (int j = 0; j < 4; ++j) {
            float s = 0.f, s2 = 0.f;
            #pragma unroll
            for (int n = 0; n < 4; ++n) {
                float v = acc[m][n][j];
                s += v; s2 += v * v;
            }
            s  = rowsum16(s);
            s2 = rowsum16(s2);
            if (l16 == 0) {
                int r = wr * 64 + m * 16 + lhi * 4 + j;
                redbuf[r * 8 + wcn * 2 + 0] = s;
                redbuf[r * 8 + wcn * 2 + 1] = s2;
            }
        }
    }
    // drain dummy stage (wrapped kt) before kernel end; redbuf is disjoint from As/Bs
    VWALL;
    __syncthreads();

    // pass 2: combine wave pair per 128-col group (float4 broadcast), normalize, clip, store
    const int p2 = (wcn & 2) * 2;
    #pragma unroll
    for (int m = 0; m < 4; ++m) {
        #pragma unroll
        for (int j = 0; j < 4; ++j) {
            const int r = wr * 64 + m * 16 + lhi * 4 + j;
            const float4 q = *(const float4*)&redbuf[r * 8 + p2];
            const float mean = (q.x + q.z) * (1.0f / 128.0f);
            const float var  = (q.y + q.w) * (1.0f / 128.0f) - mean * mean;
            const float rstd = rsqrtf(var + EPS);
            float* orow = out + (size_t)(brow * BM + r) * OUT_COLS + bcol * BN + wcn * 64 + l16;
            #pragma unroll
            for (int n = 0; n < 4; ++n) {
                float v = (acc[m][n][j] - mean) * rstd;
                v = fminf(fmaxf(v, -1.0f), 1.0f);
                orow[n * 16] = v;
            }
        }
    }
}

extern "C" void kernel_launch(void* const* d_in, const int* in_sizes, int n_in,
                              void* d_out, int out_size, void* d_ws, size_t ws_size,
                              hipStream_t stream) {
    const float* x    = (const float*)d_in[0];   // [8192][2048]
    const float* w    = (const float*)d_in[1];   // [4096][2048]
    const float* bias = (const float*)d_in[2];   // [4096]
    float* out        = (float*)d_out;           // [8192][4096]

    unsigned short* xb = (unsigned short*)d_ws;
    unsigned short* wb = xb + (size_t)B_ROWS * K_DIM;

    cvt_all<<<3072, 256, 0, stream>>>(x, w, xb, wb);

    dim3 grid((B_ROWS / BM) * (OUT_COLS / BN));   // 64 * 16 = 1024
    gemm_gn<<<grid, 512, 0, stream>>>(xb, wb, bias, out);
}

// Round 10
// 155.351 us; speedup vs baseline: 1.1723x; 1.1723x over previous
//
#include <hip/hip_runtime.h>
#include <hip/hip_bf16.h>

// Problem dims (fixed by reference)
#define B_ROWS   8192
#define K_DIM    2048
#define OUT_COLS 4096
#define EPS      1e-5f

// 256x256 C-tile, BK=64, 1024 threads = 16 waves (4M x 4N), per-wave 64x64.
// 4 waves/SIMD (VGPR<=128 via launch_bounds) amortize per-phase overhead.
// Double-buffered LDS, stage 1 K-tile ahead, vmcnt(0)+barrier once per K-tile
// (loads drained a full K-tile ~2300cyc after issue >> 900cyc latency).
#define BM 256
#define BN 256
#define BK 64
#define NT (K_DIM / BK)   // 32 K-tiles

using f32x4  = __attribute__((ext_vector_type(4))) float;
using bf16x8 = __attribute__((ext_vector_type(8))) short;   // 8 bf16 = 4 VGPRs

__device__ __forceinline__ unsigned short f2bf_rn(float f) {
    unsigned u = __builtin_bit_cast(unsigned, f);
    u += 0x7FFFu + ((u >> 16) & 1u);   // RNE (inputs finite)
    return (unsigned short)(u >> 16);
}

__global__ void cvt_all(const float* __restrict__ x, const float* __restrict__ w,
                        unsigned short* __restrict__ xb, unsigned short* __restrict__ wb) {
    const int n4x = (B_ROWS * K_DIM) / 4;
    const int n4w = (OUT_COLS * K_DIM) / 4;
    int stride = gridDim.x * blockDim.x;
    for (int i = blockIdx.x * blockDim.x + threadIdx.x; i < n4x + n4w; i += stride) {
        const float4* src; ushort4* dst; int j;
        if (i < n4x) { src = (const float4*)x; dst = (ushort4*)xb; j = i; }
        else         { src = (const float4*)w; dst = (ushort4*)wb; j = i - n4x; }
        float4 v = src[j];
        ushort4 r;
        r.x = f2bf_rn(v.x); r.y = f2bf_rn(v.y); r.z = f2bf_rn(v.z); r.w = f2bf_rn(v.w);
        dst[j] = r;
    }
}

__device__ __forceinline__ void gload16(const unsigned short* src, unsigned short* lds) {
    __builtin_amdgcn_global_load_lds((const __attribute__((address_space(1))) void*)src,
                                     (__attribute__((address_space(3))) void*)lds,
                                     16, 0, 0);
}

// 16-lane row sum via DPP row_ror (pure VALU): all 16 lanes get the total
__device__ __forceinline__ float rowsum16(float v) {
    int x;
    x = __builtin_amdgcn_update_dpp(0, __builtin_bit_cast(int, v), 0x121, 0xF, 0xF, true);
    v += __builtin_bit_cast(float, x);
    x = __builtin_amdgcn_update_dpp(0, __builtin_bit_cast(int, v), 0x122, 0xF, 0xF, true);
    v += __builtin_bit_cast(float, x);
    x = __builtin_amdgcn_update_dpp(0, __builtin_bit_cast(int, v), 0x124, 0xF, 0xF, true);
    v += __builtin_bit_cast(float, x);
    x = __builtin_amdgcn_update_dpp(0, __builtin_bit_cast(int, v), 0x128, 0xF, 0xF, true);
    v += __builtin_bit_cast(float, x);
    return v;
}

#define VWALL asm volatile("s_waitcnt vmcnt(0)" ::: "memory")
#define BAR   __builtin_amdgcn_s_barrier()

// stage one half-tile (128 rows x 64 k) with 1024 threads = 1 gload/thread;
// linear LDS dest, per-row XOR-permuted coalesced global source (r7-proven)
#define STA(BUF, H, KT) gload16(Ag + (H)*262144 + (KT)*64 + goffA, &As[BUF][(H)*8192 + ldsA])
#define STB(BUF, H, KT) gload16(Bg + (H)*262144 + (KT)*64 + goffA, &Bs[BUF][(H)*8192 + ldsA])

// one kk-phase: 4 A-frags + 4 B-frags (8 x ds_read_b128, conflict-free) + 16 MFMA
#define PHASE(BUF, CSW) do {                                                        \
    bf16x8 af[4], bb[4];                                                            \
    _Pragma("unroll") for (int m = 0; m < 4; ++m)                                   \
        af[m] = *(const bf16x8*)&As[BUF][abase + m*1024 + (CSW)];                   \
    _Pragma("unroll") for (int n = 0; n < 4; ++n)                                   \
        bb[n] = *(const bf16x8*)&Bs[BUF][bbase + n*1024 + (CSW)];                   \
    __builtin_amdgcn_s_setprio(1);                                                  \
    _Pragma("unroll") for (int m = 0; m < 4; ++m)                                   \
      _Pragma("unroll") for (int n = 0; n < 4; ++n)                                 \
        acc[m][n] = __builtin_amdgcn_mfma_f32_16x16x32_bf16(                        \
            af[m], bb[n], acc[m][n], 0, 0, 0);                                      \
    __builtin_amdgcn_s_setprio(0);                                                  \
  } while (0)

// one K-tile: stage next tile (4 gloads) -> 2 kk-phases -> vmcnt(0) -> barrier.
// Stages target the non-read buffer; the previous tile-boundary barrier ordered
// all readers of that buffer before these overwrites. vmcnt(0) drains loads
// issued a full K-tile earlier (landed) plus this tile's (aged ~2300 cyc).
#define KTILE(BUF, NB, KTN) do {                                                    \
    STA(NB, 0, KTN); STA(NB, 1, KTN);                                               \
    STB(NB, 0, KTN); STB(NB, 1, KTN);                                               \
    PHASE(BUF, csw0);                                                               \
    PHASE(BUF, csw1);                                                               \
    VWALL;                                                                          \
    BAR;                                                                            \
  } while (0)

__global__ __launch_bounds__(1024, 4) void gemm_gn(const unsigned short* __restrict__ A,
                                                   const unsigned short* __restrict__ Bw,
                                                   const float* __restrict__ bias,
                                                   float* __restrict__ out) {
    __shared__ __align__(16) unsigned short As[2][16384];   // 2 x 32 KB
    __shared__ __align__(16) unsigned short Bs[2][16384];   // 2 x 32 KB
    __shared__ __align__(16) float redbuf[256 * 8];         // 8 KB GN scratch

    const int tid  = threadIdx.x;
    const int lane = tid & 63;
    const int wave = tid >> 6;        // 0..15
    const int wr   = wave >> 2;       // 0..3 (M)
    const int wcn  = wave & 3;        // 0..3 (N)
    const int l16  = lane & 15;
    const int lhi  = lane >> 4;

    // T1: XCD-aware bijective swizzle (512 % 8 == 0)
    const int bid  = blockIdx.x;
    const int swz  = (bid & 7) * (gridDim.x >> 3) + (bid >> 3);
    const int brow = swz >> 4;        // 0..31
    const int bcol = swz & 15;        // 0..15

    // staging offsets: slot s = tid (1024 slots/half-tile); row s>>3, chunk (s&7)^(row&7)
    int goffA, ldsA;
    {
        int s = tid;  int r = s >> 3;
        goffA = r * K_DIM + (((s & 7) ^ (r & 7)) * 8);
        ldsA  = s * 8;
    }
    const unsigned short* Ag = A  + (size_t)brow * BM * K_DIM;
    const unsigned short* Bg = Bw + (size_t)bcol * BN * K_DIM;

    // fragment-read offsets: row r, chunk c = kk*4+lhi, physical chunk c^(r&7)
    const int csw0  = ((0 * 4 + lhi) ^ (l16 & 7)) * 8;
    const int csw1  = ((1 * 4 + lhi) ^ (l16 & 7)) * 8;
    const int abase = (wr >> 1) * 8192 + ((wr & 1) * 64 + l16) * 64;
    const int bbase = (wcn >> 1) * 8192 + ((wcn & 1) * 64 + l16) * 64;

    // bias folded into accumulator init
    f32x4 acc[4][4];
    {
        float bv[4];
        #pragma unroll
        for (int n = 0; n < 4; ++n)
            bv[n] = bias[bcol * BN + wcn * 64 + n * 16 + l16];
        #pragma unroll
        for (int m = 0; m < 4; ++m)
            #pragma unroll
            for (int n = 0; n < 4; ++n)
                #pragma unroll
                for (int j = 0; j < 4; ++j)
                    acc[m][n][j] = bv[n];
    }

    // ---- prologue: stage tile 0 only, drain, publish
    STA(0, 0, 0); STA(0, 1, 0);
    STB(0, 0, 0); STB(0, 1, 0);
    VWALL;
    BAR;

    // ---- main loop: 32 K-tiles in 16 statically-buffered pairs;
    // last stage wraps to kt=0 (dummy into buf1's partner, drained in-loop)
    #pragma unroll 1
    for (int it = 0; it < NT / 2; ++it) {
        const int kt = it * 2;
        KTILE(0, 1, kt + 1);
        KTILE(1, 0, (kt + 2) & (NT - 1));
    }

    // ---- epilogue: GroupNorm over 128-col groups (block-local), clip, store ----
    // pass 1: per-row (s, s2) over this wave's 64 cols; DPP reduce into redbuf.
    // C/D layout (16x16): col = lane&15, row = (lane>>4)*4 + j
    #pragma unroll
    for (int m = 0; m < 4; ++m) {
        #pragma unroll
        for (int j = 0; j < 4; ++j) {
            float s = 0.f, s2 = 0.f;
            #pragma unroll
            for (int n = 0; n < 4; ++n) {
                float v = acc[m][n][j];
                s += v; s2 += v * v;
            }
            s  = rowsum16(s);
            s2 = rowsum16(s2);
            if (l16 == 0) {
                int r = wr * 64 + m * 16 + lhi * 4 + j;
                redbuf[r * 8 + wcn * 2 + 0] = s;
                redbuf[r * 8 + wcn * 2 + 1] = s2;
            }
        }
    }
    __syncthreads();

    // pass 2: combine wave pair per 128-col group (float4 broadcast), normalize, clip, store
    const int p2 = (wcn & 2) * 2;
    #pragma unroll
    for (int m = 0; m < 4; ++m) {
        #pragma unroll
        for (int j = 0; j < 4; ++j) {
            const int r = wr * 64 + m * 16 + lhi * 4 + j;
            const float4 q = *(const float4*)&redbuf[r * 8 + p2];
            const float mean = (q.x + q.z) * (1.0f / 128.0f);
            const float var  = (q.y + q.w) * (1.0f / 128.0f) - mean * mean;
            const float rstd = rsqrtf(var + EPS);
            float* orow = out + (size_t)(brow * BM + r) * OUT_COLS + bcol * BN + wcn * 64 + l16;
            #pragma unroll
            for (int n = 0; n < 4; ++n) {
                float v = (acc[m][n][j] - mean) * rstd;
                v = fminf(fmaxf(v, -1.0f), 1.0f);
                orow[n * 16] = v;
            }
        }
    }
}

extern "C" void kernel_launch(void* const* d_in, const int* in_sizes, int n_in,
                              void* d_out, int out_size, void* d_ws, size_t ws_size,
                              hipStream_t stream) {
    const float* x    = (const float*)d_in[0];   // [8192][2048]
    const float* w    = (const float*)d_in[1];   // [4096][2048]
    const float* bias = (const float*)d_in[2];   // [4096]
    float* out        = (float*)d_out;           // [8192][4096]

    unsigned short* xb = (unsigned short*)d_ws;
    unsigned short* wb = xb + (size_t)B_ROWS * K_DIM;

    cvt_all<<<3072, 256, 0, stream>>>(x, w, xb, wb);

    dim3 grid((B_ROWS / BM) * (OUT_COLS / BN));   // 32 * 16 = 512
    gemm_gn<<<grid, 1024, 0, stream>>>(xb, wb, bias, out);
}